// Round 1
// baseline (1146.719 us; speedup 1.0000x reference)
//
// Round 1: full Mamba forward. bf16-MFMA GEMMs (fp32->bf16 staged), chunked
// parallel scan (32 chunks x 32 steps, 3 passes), fused conv/gate/residual.
#include <hip/hip_runtime.h>

#define D_MODEL 768
#define D_INNER 1536
#define D_XZ    3072
#define D_STATE 16
#define LSEQ    1024
#define NCHUNK  32
#define CLEN    32   // NCHUNK*CLEN == LSEQ

typedef float  floatx4 __attribute__((ext_vector_type(4)));
typedef __bf16 bf16x4  __attribute__((ext_vector_type(4)));
typedef __bf16 bf16x8  __attribute__((ext_vector_type(8)));

__device__ __forceinline__ float softplus_f(float x) {
  // stable: max(x,0) + log1p(exp(-|x|))
  float e = __expf(-fabsf(x));
  return fmaxf(x, 0.f) + __logf(1.f + e);
}
__device__ __forceinline__ float silu_f(float x) {
  return x / (1.f + __expf(-x));
}

// ---------------- embed gather ----------------
__global__ __launch_bounds__(256) void k_gather(const float* __restrict__ embed,
                                                const int* __restrict__ idx,
                                                float* __restrict__ x) {
  int t = blockIdx.x;
  int tok = idx[t];
  const float* src = embed + (size_t)tok * D_MODEL;
  float* dst = x + (size_t)t * D_MODEL;
  for (int c = threadIdx.x; c < D_MODEL; c += 256) dst[c] = src[c];
}

// ---------------- rmsnorm: one wave per row (768 = 12*64) ----------------
__global__ __launch_bounds__(256) void k_rmsnorm(const float* __restrict__ x,
                                                 const float* __restrict__ w,
                                                 float* __restrict__ o) {
  int lane = threadIdx.x & 63;
  int row = blockIdx.x * 4 + (threadIdx.x >> 6);
  const float* xr = x + (size_t)row * D_MODEL;
  float v[12];
  float ss = 0.f;
#pragma unroll
  for (int i = 0; i < 12; i++) { v[i] = xr[lane + i * 64]; ss += v[i] * v[i]; }
#pragma unroll
  for (int m = 32; m; m >>= 1) ss += __shfl_xor(ss, m, 64);
  float r = rsqrtf(ss * (1.f / 768.f) + 1e-5f);
  float* orow = o + (size_t)row * D_MODEL;
#pragma unroll
  for (int i = 0; i < 12; i++) orow[lane + i * 64] = v[i] * r * w[lane + i * 64];
}

// ---------------- NT GEMM: C[m,n] = res[m,n] + sum_k A[m,k]*B[n,k] ----------------
// A: MxK row-major fp32, B: NxK row-major fp32. M%128==0, N%128==0, K%32==0.
// bf16 MFMA 16x16x32, 128x128 block tile, 4 waves each 64x64.
__global__ __launch_bounds__(256) void k_gemm_nt(const float* __restrict__ A,
                                                 const float* __restrict__ B,
                                                 const float* res, float* C,
                                                 int M, int N, int K) {
  __shared__ __attribute__((aligned(16))) __bf16 As[128 * 32];
  __shared__ __attribute__((aligned(16))) __bf16 Bs[128 * 32];
  const int tid = threadIdx.x;
  const int lane = tid & 63, wave = tid >> 6;
  const int wm = (wave & 1) * 64, wn = (wave >> 1) * 64;
  const int fr = lane & 15;          // m (A) / n (B) within 16
  const int kq = (lane >> 4) * 8;    // k base within 32
  const int quad = lane >> 4;
  const int Mblk = blockIdx.y * 128, Nblk = blockIdx.x * 128;
  const int c4 = (tid & 7) * 4;      // float4 column
  const int r0 = tid >> 3;           // 0..31

  const float* Ab = A + (size_t)(Mblk + r0) * K + c4;
  const float* Bb = B + (size_t)(Nblk + r0) * K + c4;

  floatx4 acc[4][4];
#pragma unroll
  for (int i = 0; i < 4; i++)
#pragma unroll
    for (int j = 0; j < 4; j++) {
      floatx4 z = {0.f, 0.f, 0.f, 0.f};
      acc[i][j] = z;
    }

  for (int k0 = 0; k0 < K; k0 += 32) {
    __syncthreads();
#pragma unroll
    for (int i = 0; i < 4; i++) {
      float4 va = *(const float4*)(Ab + (size_t)(32 * i) * K + k0);
      float4 vb = *(const float4*)(Bb + (size_t)(32 * i) * K + k0);
      bf16x4 ba, bb;
      ba[0] = (__bf16)va.x; ba[1] = (__bf16)va.y; ba[2] = (__bf16)va.z; ba[3] = (__bf16)va.w;
      bb[0] = (__bf16)vb.x; bb[1] = (__bf16)vb.y; bb[2] = (__bf16)vb.z; bb[3] = (__bf16)vb.w;
      *(bf16x4*)&As[(r0 + 32 * i) * 32 + c4] = ba;
      *(bf16x4*)&Bs[(r0 + 32 * i) * 32 + c4] = bb;
    }
    __syncthreads();
    bf16x8 af[4], bf[4];
#pragma unroll
    for (int mt = 0; mt < 4; mt++) af[mt] = *(bf16x8*)&As[(wm + mt * 16 + fr) * 32 + kq];
#pragma unroll
    for (int nt = 0; nt < 4; nt++) bf[nt] = *(bf16x8*)&Bs[(wn + nt * 16 + fr) * 32 + kq];
#pragma unroll
    for (int mt = 0; mt < 4; mt++)
#pragma unroll
      for (int nt = 0; nt < 4; nt++)
        acc[mt][nt] = __builtin_amdgcn_mfma_f32_16x16x32_bf16(af[mt], bf[nt], acc[mt][nt], 0, 0, 0);
  }

#pragma unroll
  for (int mt = 0; mt < 4; mt++)
#pragma unroll
    for (int nt = 0; nt < 4; nt++) {
      int r = Mblk + wm + mt * 16 + quad * 4;
      int c = Nblk + wn + nt * 16 + fr;
#pragma unroll
      for (int i = 0; i < 4; i++) {
        size_t o = (size_t)(r + i) * N + c;
        float v = acc[mt][nt][i];
        if (res) v += res[o];
        C[o] = v;
      }
    }
}

// ---------------- depthwise causal conv (k=4) + bias + silu ----------------
__global__ __launch_bounds__(256) void k_conv(const float* __restrict__ xz,
                                              const float* __restrict__ cw,
                                              const float* __restrict__ cb,
                                              float* __restrict__ xc) {
  int d = blockIdx.x * 256 + threadIdx.x;
  int t = blockIdx.y;
  float4 w = *(const float4*)(cw + (size_t)d * 4);
  float wv[4] = {w.x, w.y, w.z, w.w};
  float acc = cb[d];
#pragma unroll
  for (int j = 0; j < 4; j++) {
    int ts = t - 3 + j;
    if (ts >= 0) acc += wv[j] * xz[(size_t)ts * D_XZ + d];
  }
  xc[(size_t)t * D_INNER + d] = silu_f(acc);
}

// ---------------- xp = xc @ W_x^T  (1024 x 33, K=1536), one wave per row ----------------
__global__ __launch_bounds__(256) void k_xp(const float* __restrict__ xc,
                                            const float* __restrict__ Wx,
                                            float* __restrict__ xp) {
  int lane = threadIdx.x & 63;
  int t = blockIdx.x * 4 + (threadIdx.x >> 6);
  const float* xr = xc + (size_t)t * D_INNER;
  float acc[33];
#pragma unroll
  for (int j = 0; j < 33; j++) acc[j] = 0.f;
  for (int k0 = 0; k0 < D_INNER; k0 += 64) {
    float xv = xr[k0 + lane];
#pragma unroll
    for (int j = 0; j < 33; j++) acc[j] += xv * Wx[(size_t)j * D_INNER + k0 + lane];
  }
#pragma unroll
  for (int j = 0; j < 33; j++) {
    float v = acc[j];
#pragma unroll
    for (int m = 32; m; m >>= 1) v += __shfl_xor(v, m, 64);
    if (lane == j) xp[(size_t)t * 33 + j] = v;
  }
}

// ---------------- scan phase 1: per-chunk scan with h0=0 + cumprod(dA) ----------------
__global__ __launch_bounds__(256) void k_scan1(const float* __restrict__ xp,
                                               const float* __restrict__ xc,
                                               const float* __restrict__ dtw,
                                               const float* __restrict__ dtb,
                                               const float* __restrict__ Alog,
                                               float* __restrict__ hend,
                                               float* __restrict__ Pp) {
  __shared__ float sxp[CLEN * 33];
  int c = blockIdx.x;
  int d = blockIdx.y * 256 + threadIdx.x;
  for (int i = threadIdx.x; i < CLEN * 33; i += 256) sxp[i] = xp[(size_t)c * CLEN * 33 + i];
  __syncthreads();
  float Av[16];
#pragma unroll
  for (int n = 0; n < 16; n++) Av[n] = -__expf(Alog[(size_t)d * 16 + n]);
  float w_ = dtw[d], b_ = dtb[d];
  float h[16], P[16];
#pragma unroll
  for (int n = 0; n < 16; n++) { h[n] = 0.f; P[n] = 1.f; }
  const float* xcc = xc + (size_t)(c * CLEN) * D_INNER + d;
  for (int tl = 0; tl < CLEN; tl++) {
    float dtr = sxp[tl * 33];
    float xv = xcc[(size_t)tl * D_INNER];
    float dt = softplus_f(dtr * w_ + b_);
    float sx = dt * xv;
#pragma unroll
    for (int n = 0; n < 16; n++) {
      float dA = __expf(dt * Av[n]);
      h[n] = dA * h[n] + sx * sxp[tl * 33 + 1 + n];
      P[n] *= dA;
    }
  }
  size_t o = ((size_t)c * D_INNER + d) * 16;
#pragma unroll
  for (int n = 0; n < 16; n++) { hend[o + n] = h[n]; Pp[o + n] = P[n]; }
}

// ---------------- scan combine: sequential over chunks, parallel over (d,n) ----------------
__global__ __launch_bounds__(256) void k_comb(const float* __restrict__ hend,
                                              const float* __restrict__ Pp,
                                              float* __restrict__ h0) {
  int i = blockIdx.x * 256 + threadIdx.x;  // 0 .. 24575
  float h = 0.f;
  for (int c = 0; c < NCHUNK; c++) {
    h0[(size_t)c * (D_INNER * 16) + i] = h;
    h = Pp[(size_t)c * (D_INNER * 16) + i] * h + hend[(size_t)c * (D_INNER * 16) + i];
  }
}

// ---------------- scan phase 2: rescan from h0, y-reduce, +D skip, *silu(z) ----------------
__global__ __launch_bounds__(256) void k_scan2(const float* __restrict__ xp,
                                               const float* __restrict__ xc,
                                               const float* __restrict__ xz,
                                               const float* __restrict__ dtw,
                                               const float* __restrict__ dtb,
                                               const float* __restrict__ Alog,
                                               const float* __restrict__ Dp,
                                               const float* __restrict__ h0,
                                               float* __restrict__ g) {
  __shared__ float sxp[CLEN * 33];
  int c = blockIdx.x;
  int d = blockIdx.y * 256 + threadIdx.x;
  for (int i = threadIdx.x; i < CLEN * 33; i += 256) sxp[i] = xp[(size_t)c * CLEN * 33 + i];
  __syncthreads();
  float Av[16];
#pragma unroll
  for (int n = 0; n < 16; n++) Av[n] = -__expf(Alog[(size_t)d * 16 + n]);
  float w_ = dtw[d], b_ = dtb[d], Dv = Dp[d];
  float h[16];
  size_t ho = ((size_t)c * D_INNER + d) * 16;
#pragma unroll
  for (int n = 0; n < 16; n++) h[n] = h0[ho + n];
  for (int tl = 0; tl < CLEN; tl++) {
    int t = c * CLEN + tl;
    float dtr = sxp[tl * 33];
    float xv = xc[(size_t)t * D_INNER + d];
    float dt = softplus_f(dtr * w_ + b_);
    float sx = dt * xv;
    float y = 0.f;
#pragma unroll
    for (int n = 0; n < 16; n++) {
      float dA = __expf(dt * Av[n]);
      h[n] = dA * h[n] + sx * sxp[tl * 33 + 1 + n];
      y += h[n] * sxp[tl * 33 + 17 + n];
    }
    float z = xz[(size_t)t * D_XZ + D_INNER + d];
    g[(size_t)t * D_INNER + d] = (y + xv * Dv) * silu_f(z);
  }
}

extern "C" void kernel_launch(void* const* d_in, const int* in_sizes, int n_in,
                              void* d_out, int out_size, void* d_ws, size_t ws_size,
                              hipStream_t stream) {
  const int*   idx     = (const int*)d_in[0];
  const float* embed   = (const float*)d_in[1];
  const float* norm_w  = (const float*)d_in[2];
  const float* W_in    = (const float*)d_in[3];
  const float* conv_w  = (const float*)d_in[4];
  const float* conv_b  = (const float*)d_in[5];
  const float* W_x     = (const float*)d_in[6];
  const float* dt_w    = (const float*)d_in[7];
  const float* dt_b    = (const float*)d_in[8];
  const float* A_log   = (const float*)d_in[9];
  const float* Dp      = (const float*)d_in[10];
  const float* out_w   = (const float*)d_in[11];
  const float* norm_fw = (const float*)d_in[12];
  float* out = (float*)d_out;

  // workspace layout (fp32 elements), total ~41 MB
  float* x    = (float*)d_ws;          // 1024*768
  float* xn   = x    + 1024 * 768;     // 1024*768
  float* xz   = xn   + 1024 * 768;     // 1024*3072
  float* xc   = xz   + 1024 * 3072;    // 1024*1536
  float* xp   = xc   + 1024 * 1536;    // 1024*33
  float* g    = xp   + 1024 * 33;      // 1024*1536
  float* hend = g    + 1024 * 1536;    // 32*1536*16
  float* Pp   = hend + NCHUNK * D_INNER * 16;
  float* h0b  = Pp   + NCHUNK * D_INNER * 16;

  k_gather<<<1024, 256, 0, stream>>>(embed, idx, x);

  for (int l = 0; l < 4; l++) {
    k_rmsnorm<<<256, 256, 0, stream>>>(x, norm_w + l * D_MODEL, xn);
    // xz = xn @ W_in[l]^T : M=1024 N=3072 K=768
    k_gemm_nt<<<dim3(3072 / 128, 1024 / 128), 256, 0, stream>>>(
        xn, W_in + (size_t)l * D_XZ * D_MODEL, nullptr, xz, 1024, D_XZ, D_MODEL);
    k_conv<<<dim3(6, 1024), 256, 0, stream>>>(xz, conv_w + (size_t)l * D_INNER * 4,
                                              conv_b + (size_t)l * D_INNER, xc);
    k_xp<<<256, 256, 0, stream>>>(xc, W_x + (size_t)l * 33 * D_INNER, xp);
    k_scan1<<<dim3(NCHUNK, 6), 256, 0, stream>>>(xp, xc, dt_w + (size_t)l * D_INNER,
                                                 dt_b + (size_t)l * D_INNER,
                                                 A_log + (size_t)l * D_INNER * 16, hend, Pp);
    k_comb<<<(D_INNER * 16) / 256, 256, 0, stream>>>(hend, Pp, h0b);
    k_scan2<<<dim3(NCHUNK, 6), 256, 0, stream>>>(xp, xc, xz, dt_w + (size_t)l * D_INNER,
                                                 dt_b + (size_t)l * D_INNER,
                                                 A_log + (size_t)l * D_INNER * 16,
                                                 Dp + (size_t)l * D_INNER, h0b, g);
    // x = x + g @ out_w[l]^T : M=1024 N=768 K=1536 (fused residual, in-place safe)
    k_gemm_nt<<<dim3(768 / 128, 1024 / 128), 256, 0, stream>>>(
        g, out_w + (size_t)l * D_MODEL * D_INNER, x, x, 1024, D_MODEL, D_INNER);
  }

  k_rmsnorm<<<256, 256, 0, stream>>>(x, norm_fw, xn);
  // logits = xn @ embed^T : M=1024 N=32000 K=768
  k_gemm_nt<<<dim3(32000 / 128, 1024 / 128), 256, 0, stream>>>(
      xn, embed, nullptr, out, 1024, 32000, D_MODEL);
}